// Round 3
// baseline (553.271 us; speedup 1.0000x reference)
//
#include <hip/hip_runtime.h>

#define NRAYS 4096
#define PSAMP 254      // 231 inner + 23 outer samples
#define NIN   231
#define GR    160
#define GR2   25600
#define GR3   4096000
#define SROW  136      // h-buffer row stride in bf16 elems (272 B, 16B-aligned)
#define FROW  48       // feat row stride in bf16 elems (96 B, 16B-aligned)

typedef __attribute__((ext_vector_type(8))) short bf16x8;
typedef __attribute__((ext_vector_type(4))) float f32x4;

__device__ __forceinline__ unsigned short f2bf(float x) {
    union { float f; unsigned u; } v; v.f = x;
    return (unsigned short)((v.u + 0x7fffu + ((v.u >> 16) & 1u)) >> 16);
}
__device__ __forceinline__ float bfhalf(unsigned w, int hi) {
    union { unsigned u; float f; } v;
    v.u = hi ? (w & 0xffff0000u) : (w << 16);
    return v.f;
}
__device__ __forceinline__ float sigmoidf_(float x) { return 1.0f / (1.0f + __expf(-x)); }

// ---------------- weight prepack (both paths) ----------------
// Pack W[K x N] (row-major fp32) into MFMA B-frag order bf16; zero-pad k>=K, n>=N.
__global__ void prepack(const float* __restrict__ w, unsigned short* __restrict__ out,
                        int K, int N, int ldw, int NT, int KS) {
    const int idx = blockIdx.x * 256 + threadIdx.x;
    if (idx >= NT * KS * 64) return;
    const int l  = idx & 63, f = idx >> 6;
    const int ks = f % KS,  nt = f / KS;
    const int n  = nt * 16 + (l & 15);
    const int k0 = ks * 32 + (l >> 4) * 8;
    unsigned p[4];
    #pragma unroll
    for (int q = 0; q < 4; q++) {
        const int ka = k0 + 2 * q, kb = ka + 1;
        const float va = (ka < K && n < N) ? w[ka * ldw + n] : 0.0f;
        const float vb = (kb < K && n < N) ? w[kb * ldw + n] : 0.0f;
        p[q] = (unsigned)f2bf(va) | ((unsigned)f2bf(vb) << 16);
    }
    uint4 v; v.x = p[0]; v.y = p[1]; v.z = p[2]; v.w = p[3];
    ((uint4*)out)[idx] = v;
}

// ---------------- k0 repack: [C][x][y][z] fp32 -> [voxel][16] bf16 ----------------
__global__ __launch_bounds__(256) void pack_k0(const float* __restrict__ k0g,
                                               unsigned short* __restrict__ pk) {
    const int v = blockIdx.x * 256 + threadIdx.x;
    if (v >= GR3) return;
    unsigned d[8];
    #pragma unroll
    for (int c = 0; c < 6; c++) {
        const float a = k0g[(size_t)(2*c  ) * GR3 + v];
        const float b = k0g[(size_t)(2*c+1) * GR3 + v];
        d[c] = (unsigned)f2bf(a) | ((unsigned)f2bf(b) << 16);
    }
    d[6] = 0u; d[7] = 0u;
    uint4* o = (uint4*)(pk + (size_t)v * 16);
    uint4 v0; v0.x = d[0]; v0.y = d[1]; v0.z = d[2]; v0.w = d[3];
    uint4 v1; v1.x = d[4]; v1.y = d[5]; v1.z = d[6]; v1.w = d[7];
    o[0] = v0; o[1] = v1;
}

// ---------------- kernel A: geometry + density + scan + packed-k0 gather ----------------
__global__ __launch_bounds__(256) void voxgo_gather(
    const float* __restrict__ rays_o, const float* __restrict__ rays_d,
    const float* __restrict__ viewdirs, const float* __restrict__ dg,
    const unsigned short* __restrict__ pk0,
    unsigned short* __restrict__ feat, float* __restrict__ wgt,
    float* __restrict__ out)
{
    const int r = blockIdx.x, tid = threadIdx.x;
    __shared__ float sc[256];

    const float ox = rays_o[3*r+0], oy = rays_o[3*r+1], oz = rays_o[3*r+2];
    float dxv = rays_d[3*r+0], dyv = rays_d[3*r+1], dzv = rays_d[3*r+2];
    const float vdx = viewdirs[3*r+0], vdy = viewdirs[3*r+1], vdz = viewdirs[3*r+2];
    const float rinv = rsqrtf(dxv*dxv + dyv*dyv + dzv*dzv);
    dxv *= rinv; dyv *= rinv; dzv *= rinv;

    float t;
    if (tid < NIN) {
        t = ((float)tid + 0.5f) * (2.0f * 1.7320508075688772f / 231.0f);
    } else {
        const float lstep = 0.999f / 23.0f;
        const int j = tid - NIN;                   // tids 254,255: junk; weight=0
        const float L0 = 1.0f - (float)j * lstep;
        const float L1 = 1.0f - (float)(j+1) * lstep;
        t = 1.7320508075688772f * (1.0f/L0 + 1.0f/L1);
    }

    float px = fmaf(dxv, t, ox), py = fmaf(dyv, t, oy), pz = fmaf(dzv, t, oz);
    const float nrm = fmaxf(fabsf(px), fmaxf(fabsf(py), fabsf(pz)));
    if (nrm > 1.0f) {
        const float s = (1.2f - 0.2f / nrm) / nrm;
        px *= s; py *= s; pz *= s;
    }
    const float gsc = 159.0f / 2.4f;
    const float gx = fminf(fmaxf((px + 1.2f) * gsc, 0.0f), 159.0f);
    const float gy = fminf(fmaxf((py + 1.2f) * gsc, 0.0f), 159.0f);
    const float gz = fminf(fmaxf((pz + 1.2f) * gsc, 0.0f), 159.0f);
    const int x0 = min((int)gx, GR-2), y0 = min((int)gy, GR-2), z0 = min((int)gz, GR-2);
    const float fx = gx - (float)x0, fy = gy - (float)y0, fz = gz - (float)z0;
    const int base = x0*GR2 + y0*GR + z0;

    // density (fp32 grid -> exact same numerics as before)
    const float d000 = dg[base],        d001 = dg[base+1];
    const float d010 = dg[base+GR],     d011 = dg[base+GR+1];
    const float d100 = dg[base+GR2],    d101 = dg[base+GR2+1];
    const float d110 = dg[base+GR2+GR], d111 = dg[base+GR2+GR+1];
    const float c00 = d000*(1.0f-fz) + d001*fz;
    const float c01 = d010*(1.0f-fz) + d011*fz;
    const float c10 = d100*(1.0f-fz) + d101*fz;
    const float c11 = d110*(1.0f-fz) + d111*fz;
    const float dens = (c00*(1.0f-fy) + c01*fy)*(1.0f-fx) + (c10*(1.0f-fy) + c11*fy)*fx;

    const float ACT_SHIFT = -9.21024036697535f;
    const float alpha = (tid < PSAMP) ? sigmoidf_(dens + ACT_SHIFT) : 0.0f;

    // product scan of (1-alpha)
    sc[tid] = 1.0f - alpha;
    __syncthreads();
    #pragma unroll
    for (int off = 1; off < 256; off <<= 1) {
        const float v = (tid >= off) ? sc[tid - off] : 1.0f;
        __syncthreads();
        sc[tid] *= v;
        __syncthreads();
    }
    const float T_excl = (tid == 0) ? 1.0f : sc[tid-1];
    wgt[(size_t)r*256 + tid] = alpha * T_excl;
    if (tid < 3) out[3*r + tid] = sc[PSAMP-1];     // init with alphainv_last*BG

    // ---- packed k0 gather: 8 corners x 32 B ----
    const int off_[8] = {0, 1, GR, GR+1, GR2, GR2+1, GR2+GR, GR2+GR+1};
    unsigned crw[8][8];
    #pragma unroll
    for (int i = 0; i < 8; i++) {
        const uint4* p = (const uint4*)(pk0 + (size_t)(base + off_[i]) * 16);
        const uint4 a = p[0], b = p[1];
        crw[i][0]=a.x; crw[i][1]=a.y; crw[i][2]=a.z; crw[i][3]=a.w;
        crw[i][4]=b.x; crw[i][5]=b.y; crw[i][6]=b.z; crw[i][7]=b.w;
    }
    const float wx0 = 1.0f-fx, wy0 = 1.0f-fy, wz0 = 1.0f-fz;
    float w8[8];
    w8[0]=wx0*wy0*wz0; w8[1]=wx0*wy0*fz; w8[2]=wx0*fy*wz0; w8[3]=wx0*fy*fz;
    w8[4]=fx*wy0*wz0;  w8[5]=fx*wy0*fz;  w8[6]=fx*fy*wz0;  w8[7]=fx*fy*fz;

    float fva[40];
    #pragma unroll
    for (int c = 0; c < 12; c++) {
        const int wd = c >> 1, hi = c & 1;
        float acc = 0.0f;
        #pragma unroll
        for (int i = 0; i < 8; i++) acc += w8[i] * bfhalf(crw[i][wd], hi);
        fva[c] = acc;
    }
    fva[12] = vdx; fva[13] = vdy; fva[14] = vdz;
    #pragma unroll
    for (int p = 0; p < 4; p++) {
        const float f = (float)(1 << p);
        fva[15+p] = __sinf(vdx*f);  fva[19+p] = __sinf(vdy*f);  fva[23+p] = __sinf(vdz*f);
        fva[27+p] = __cosf(vdx*f);  fva[31+p] = __cosf(vdy*f);  fva[35+p] = __cosf(vdz*f);
    }
    fva[39] = 0.0f;

    unsigned pwd[20];
    #pragma unroll
    for (int q = 0; q < 20; q++)
        pwd[q] = (unsigned)f2bf(fva[2*q]) | ((unsigned)f2bf(fva[2*q+1]) << 16);
    uint4* dst = (uint4*)(feat + ((size_t)r*256 + tid) * FROW);
    uint4 s0; s0.x=pwd[0];  s0.y=pwd[1];  s0.z=pwd[2];  s0.w=pwd[3];  dst[0]=s0;
    uint4 s1; s1.x=pwd[4];  s1.y=pwd[5];  s1.z=pwd[6];  s1.w=pwd[7];  dst[1]=s1;
    uint4 s2; s2.x=pwd[8];  s2.y=pwd[9];  s2.z=pwd[10]; s2.w=pwd[11]; dst[2]=s2;
    uint4 s3; s3.x=pwd[12]; s3.y=pwd[13]; s3.z=pwd[14]; s3.w=pwd[15]; dst[3]=s3;
    uint4 s4; s4.x=pwd[16]; s4.y=pwd[17]; s4.z=pwd[18]; s4.w=pwd[19]; dst[4]=s4;
}

// ---------------- kernel B: per-wave MLP (64-thread blocks) ----------------
__global__ __launch_bounds__(64) void voxgo_mlp(
    const unsigned short* __restrict__ feat, const float* __restrict__ wgt,
    const float* __restrict__ b0, const float* __restrict__ b1, const float* __restrict__ b2,
    const unsigned short* __restrict__ pw0, const unsigned short* __restrict__ pw1,
    const unsigned short* __restrict__ pw2, float* __restrict__ out)
{
    const int blk  = blockIdx.x;
    const int ray  = blk >> 2, wq = blk & 3;
    const int lane = threadIdx.x, quad = lane >> 4, l16 = lane & 15;
    const size_t s0 = (size_t)ray*256 + wq*64;

    __shared__ unsigned short hb[64 * SROW];
    __shared__ float red[64];

    // ---- layer 1: K=64 (pad; pw0 rows >=39 are zero so A-garbage is harmless) ----
    f32x4 acc1[4][8];
    #pragma unroll
    for (int nt = 0; nt < 8; nt++) {
        const float bz = b0[nt*16 + l16];
        #pragma unroll
        for (int mt = 0; mt < 4; mt++) { f32x4 z = {bz,bz,bz,bz}; acc1[mt][nt] = z; }
    }
    #pragma unroll
    for (int ks = 0; ks < 2; ks++) {
        bf16x8 a[4];
        #pragma unroll
        for (int mt = 0; mt < 4; mt++)
            a[mt] = *(const bf16x8*)(feat + (s0 + mt*16 + l16)*FROW + ks*32 + quad*8);
        #pragma unroll
        for (int nt = 0; nt < 8; nt++) {
            const bf16x8 b = *(const bf16x8*)(pw0 + ((nt*2 + ks)*64 + lane)*8);
            #pragma unroll
            for (int mt = 0; mt < 4; mt++)
                acc1[mt][nt] = __builtin_amdgcn_mfma_f32_16x16x32_bf16(a[mt], b, acc1[mt][nt], 0,0,0);
        }
    }
    #pragma unroll
    for (int mt = 0; mt < 4; mt++)
        #pragma unroll
        for (int nt = 0; nt < 8; nt++)
            #pragma unroll
            for (int e = 0; e < 4; e++)
                hb[(mt*16 + quad*4 + e)*SROW + nt*16 + l16] = f2bf(fmaxf(acc1[mt][nt][e], 0.0f));
    __syncthreads();

    // ---- layer 2: K=128 ----
    f32x4 acc2[4][8];
    #pragma unroll
    for (int nt = 0; nt < 8; nt++) {
        const float bz = b1[nt*16 + l16];
        #pragma unroll
        for (int mt = 0; mt < 4; mt++) { f32x4 z = {bz,bz,bz,bz}; acc2[mt][nt] = z; }
    }
    #pragma unroll
    for (int ks = 0; ks < 4; ks++) {
        bf16x8 a[4];
        #pragma unroll
        for (int mt = 0; mt < 4; mt++)
            a[mt] = *(const bf16x8*)(hb + (mt*16 + l16)*SROW + ks*32 + quad*8);
        #pragma unroll
        for (int nt = 0; nt < 8; nt++) {
            const bf16x8 b = *(const bf16x8*)(pw1 + ((nt*4 + ks)*64 + lane)*8);
            #pragma unroll
            for (int mt = 0; mt < 4; mt++)
                acc2[mt][nt] = __builtin_amdgcn_mfma_f32_16x16x32_bf16(a[mt], b, acc2[mt][nt], 0,0,0);
        }
    }
    __syncthreads();
    #pragma unroll
    for (int mt = 0; mt < 4; mt++)
        #pragma unroll
        for (int nt = 0; nt < 8; nt++)
            #pragma unroll
            for (int e = 0; e < 4; e++)
                hb[(mt*16 + quad*4 + e)*SROW + nt*16 + l16] = f2bf(fmaxf(acc2[mt][nt][e], 0.0f));
    __syncthreads();

    // ---- layer 3: N=16 (cols >=3 zero-padded) ----
    f32x4 acc3[4];
    {
        const float bz = (l16 < 3) ? b2[l16] : 0.0f;
        #pragma unroll
        for (int mt = 0; mt < 4; mt++) { f32x4 z = {bz,bz,bz,bz}; acc3[mt] = z; }
    }
    #pragma unroll
    for (int ks = 0; ks < 4; ks++) {
        const bf16x8 b = *(const bf16x8*)(pw2 + (ks*64 + lane)*8);
        #pragma unroll
        for (int mt = 0; mt < 4; mt++) {
            const bf16x8 a = *(const bf16x8*)(hb + (mt*16 + l16)*SROW + ks*32 + quad*8);
            acc3[mt] = __builtin_amdgcn_mfma_f32_16x16x32_bf16(a, b, acc3[mt], 0,0,0);
        }
    }

    // ---- epilogue: sigmoid + weighted partial sum + atomic ----
    float contrib = 0.0f;
    #pragma unroll
    for (int mt = 0; mt < 4; mt++)
        #pragma unroll
        for (int e = 0; e < 4; e++)
            contrib += wgt[s0 + mt*16 + quad*4 + e] * sigmoidf_(acc3[mt][e]);
    red[lane] = contrib;
    __syncthreads();
    if (lane < 3)
        atomicAdd(&out[3*ray + lane], red[lane] + red[lane+16] + red[lane+32] + red[lane+48]);
}

// ---------------- fallback: round-2 fused kernel ----------------
__global__ __launch_bounds__(256, 2) void voxgo_mfma(
    const float* __restrict__ rays_o, const float* __restrict__ rays_d,
    const float* __restrict__ viewdirs, const float* __restrict__ dg,
    const float* __restrict__ k0g,
    const float* __restrict__ b0, const float* __restrict__ b1,
    const float* __restrict__ b2,
    const unsigned short* __restrict__ pw0, const unsigned short* __restrict__ pw1,
    const unsigned short* __restrict__ pw2,
    float* __restrict__ out)
{
    const int r    = blockIdx.x;
    const int tid  = threadIdx.x;
    const int wv   = tid >> 6, lane = tid & 63, quad = lane >> 4, l16 = lane & 15;

    __shared__ unsigned short hbuf[4][64 * SROW];
    __shared__ float sc[256];
    __shared__ float wgt[256];
    __shared__ float redbuf[256];

    const float ox = rays_o[3*r+0], oy = rays_o[3*r+1], oz = rays_o[3*r+2];
    float dxv = rays_d[3*r+0], dyv = rays_d[3*r+1], dzv = rays_d[3*r+2];
    const float vdx = viewdirs[3*r+0], vdy = viewdirs[3*r+1], vdz = viewdirs[3*r+2];
    const float rinv = rsqrtf(dxv*dxv + dyv*dyv + dzv*dzv);
    dxv *= rinv; dyv *= rinv; dzv *= rinv;

    float t;
    if (tid < NIN) {
        t = ((float)tid + 0.5f) * (2.0f * 1.7320508075688772f / 231.0f);
    } else {
        const float lstep = 0.999f / 23.0f;
        const int j = tid - NIN;
        const float L0 = 1.0f - (float)j * lstep;
        const float L1 = 1.0f - (float)(j+1) * lstep;
        t = 1.7320508075688772f * (1.0f/L0 + 1.0f/L1);
    }

    float px = fmaf(dxv, t, ox), py = fmaf(dyv, t, oy), pz = fmaf(dzv, t, oz);
    const float nrm = fmaxf(fabsf(px), fmaxf(fabsf(py), fabsf(pz)));
    if (nrm > 1.0f) {
        const float s = (1.2f - 0.2f / nrm) / nrm;
        px *= s; py *= s; pz *= s;
    }
    const float gsc = 159.0f / 2.4f;
    const float gx = fminf(fmaxf((px + 1.2f) * gsc, 0.0f), 159.0f);
    const float gy = fminf(fmaxf((py + 1.2f) * gsc, 0.0f), 159.0f);
    const float gz = fminf(fmaxf((pz + 1.2f) * gsc, 0.0f), 159.0f);
    const int x0 = min((int)gx, GR-2), y0 = min((int)gy, GR-2), z0 = min((int)gz, GR-2);
    const float fx = gx - (float)x0, fy = gy - (float)y0, fz = gz - (float)z0;
    const int base = x0*GR2 + y0*GR + z0;

    const float d000 = dg[base],        d001 = dg[base+1];
    const float d010 = dg[base+GR],     d011 = dg[base+GR+1];
    const float d100 = dg[base+GR2],    d101 = dg[base+GR2+1];
    const float d110 = dg[base+GR2+GR], d111 = dg[base+GR2+GR+1];
    const float c00 = d000*(1.0f-fz) + d001*fz;
    const float c01 = d010*(1.0f-fz) + d011*fz;
    const float c10 = d100*(1.0f-fz) + d101*fz;
    const float c11 = d110*(1.0f-fz) + d111*fz;
    const float dens = (c00*(1.0f-fy) + c01*fy)*(1.0f-fx) + (c10*(1.0f-fy) + c11*fy)*fx;

    const float ACT_SHIFT = -9.21024036697535f;
    const float alpha = (tid < PSAMP) ? sigmoidf_(dens + ACT_SHIFT) : 0.0f;

    sc[tid] = 1.0f - alpha;
    __syncthreads();
    #pragma unroll
    for (int off = 1; off < 256; off <<= 1) {
        const float v = (tid >= off) ? sc[tid - off] : 1.0f;
        __syncthreads();
        sc[tid] *= v;
        __syncthreads();
    }
    const float T_excl = (tid == 0) ? 1.0f : sc[tid-1];
    wgt[tid] = alpha * T_excl;

    const float wx0 = 1.0f-fx, wy0 = 1.0f-fy, wz0 = 1.0f-fz;
    const float w000 = wx0*wy0*wz0, w001 = wx0*wy0*fz, w010 = wx0*fy*wz0, w011 = wx0*fy*fz;
    const float w100 = fx*wy0*wz0,  w101 = fx*wy0*fz,  w110 = fx*fy*wz0,  w111 = fx*fy*fz;

    float fv[40];
    #pragma unroll
    for (int c = 0; c < 12; c++) {
        const float* g = k0g + (size_t)c*GR3 + base;
        fv[c] = w000*g[0]      + w001*g[1]
              + w010*g[GR]     + w011*g[GR+1]
              + w100*g[GR2]    + w101*g[GR2+1]
              + w110*g[GR2+GR] + w111*g[GR2+GR+1];
    }
    fv[12] = vdx; fv[13] = vdy; fv[14] = vdz;
    #pragma unroll
    for (int p = 0; p < 4; p++) {
        const float f = (float)(1 << p);
        fv[15+p] = __sinf(vdx*f);  fv[19+p] = __sinf(vdy*f);  fv[23+p] = __sinf(vdz*f);
        fv[27+p] = __cosf(vdx*f);  fv[31+p] = __cosf(vdy*f);  fv[35+p] = __cosf(vdz*f);
    }
    fv[39] = 0.0f;

    unsigned short* hb = &hbuf[wv][0];
    {
        const int row = tid & 63;
        uint4* dst = (uint4*)(hb + row * SROW);
        #pragma unroll
        for (int i = 0; i < 8; i++) {
            unsigned p[4];
            #pragma unroll
            for (int q = 0; q < 4; q++) {
                const int e0 = i*8 + 2*q, e1 = e0 + 1;
                const unsigned lo = (e0 < 39) ? f2bf(fv[e0]) : 0u;
                const unsigned hi = (e1 < 39) ? f2bf(fv[e1]) : 0u;
                p[q] = lo | (hi << 16);
            }
            uint4 v; v.x = p[0]; v.y = p[1]; v.z = p[2]; v.w = p[3];
            dst[i] = v;
        }
    }
    __syncthreads();

    f32x4 acc1[4][8];
    #pragma unroll
    for (int nt = 0; nt < 8; nt++) {
        const float bz = b0[nt*16 + l16];
        #pragma unroll
        for (int mt = 0; mt < 4; mt++) { f32x4 z = {bz,bz,bz,bz}; acc1[mt][nt] = z; }
    }
    #pragma unroll
    for (int ks = 0; ks < 2; ks++) {
        bf16x8 a[4];
        #pragma unroll
        for (int mt = 0; mt < 4; mt++)
            a[mt] = *(const bf16x8*)(hb + (mt*16 + l16)*SROW + ks*32 + quad*8);
        #pragma unroll
        for (int nt = 0; nt < 8; nt++) {
            const bf16x8 b = *(const bf16x8*)(pw0 + ((nt*2 + ks)*64 + lane)*8);
            #pragma unroll
            for (int mt = 0; mt < 4; mt++)
                acc1[mt][nt] = __builtin_amdgcn_mfma_f32_16x16x32_bf16(a[mt], b, acc1[mt][nt], 0,0,0);
        }
    }
    #pragma unroll
    for (int mt = 0; mt < 4; mt++)
        #pragma unroll
        for (int nt = 0; nt < 8; nt++)
            #pragma unroll
            for (int e = 0; e < 4; e++)
                hb[(mt*16 + quad*4 + e)*SROW + nt*16 + l16] = f2bf(fmaxf(acc1[mt][nt][e], 0.0f));
    __syncthreads();

    f32x4 acc2[4][8];
    #pragma unroll
    for (int nt = 0; nt < 8; nt++) {
        const float bz = b1[nt*16 + l16];
        #pragma unroll
        for (int mt = 0; mt < 4; mt++) { f32x4 z = {bz,bz,bz,bz}; acc2[mt][nt] = z; }
    }
    #pragma unroll
    for (int ks = 0; ks < 4; ks++) {
        bf16x8 a[4];
        #pragma unroll
        for (int mt = 0; mt < 4; mt++)
            a[mt] = *(const bf16x8*)(hb + (mt*16 + l16)*SROW + ks*32 + quad*8);
        #pragma unroll
        for (int nt = 0; nt < 8; nt++) {
            const bf16x8 b = *(const bf16x8*)(pw1 + ((nt*4 + ks)*64 + lane)*8);
            #pragma unroll
            for (int mt = 0; mt < 4; mt++)
                acc2[mt][nt] = __builtin_amdgcn_mfma_f32_16x16x32_bf16(a[mt], b, acc2[mt][nt], 0,0,0);
        }
    }
    __syncthreads();
    #pragma unroll
    for (int mt = 0; mt < 4; mt++)
        #pragma unroll
        for (int nt = 0; nt < 8; nt++)
            #pragma unroll
            for (int e = 0; e < 4; e++)
                hb[(mt*16 + quad*4 + e)*SROW + nt*16 + l16] = f2bf(fmaxf(acc2[mt][nt][e], 0.0f));
    __syncthreads();

    f32x4 acc3[4];
    {
        const float bz = (l16 < 3) ? b2[l16] : 0.0f;
        #pragma unroll
        for (int mt = 0; mt < 4; mt++) { f32x4 z = {bz,bz,bz,bz}; acc3[mt] = z; }
    }
    #pragma unroll
    for (int ks = 0; ks < 4; ks++) {
        const bf16x8 b = *(const bf16x8*)(pw2 + (ks*64 + lane)*8);
        #pragma unroll
        for (int mt = 0; mt < 4; mt++) {
            const bf16x8 a = *(const bf16x8*)(hb + (mt*16 + l16)*SROW + ks*32 + quad*8);
            acc3[mt] = __builtin_amdgcn_mfma_f32_16x16x32_bf16(a, b, acc3[mt], 0,0,0);
        }
    }

    float contrib = 0.0f;
    #pragma unroll
    for (int mt = 0; mt < 4; mt++)
        #pragma unroll
        for (int e = 0; e < 4; e++)
            contrib += wgt[wv*64 + mt*16 + quad*4 + e] * sigmoidf_(acc3[mt][e]);
    redbuf[tid] = contrib;
    __syncthreads();
    if (tid < 3) {
        float acc_o = sc[PSAMP-1];
        #pragma unroll
        for (int w = 0; w < 4; w++)
            #pragma unroll
            for (int q = 0; q < 4; q++)
                acc_o += redbuf[w*64 + q*16 + tid];
        out[3*r + tid] = acc_o;
    }
}

extern "C" void kernel_launch(void* const* d_in, const int* in_sizes, int n_in,
                              void* d_out, int out_size, void* d_ws, size_t ws_size,
                              hipStream_t stream) {
    (void)in_sizes; (void)n_in; (void)out_size;

    // ws layout: [pw0|pw1|pw2 : 53248 B][pack_k0 : 131072000 B][feat : 100667392 B][wgt : 4194304 B]
    const size_t PWB   = 53248;
    const size_t PACKB = 131072000ull;
    const size_t FEATB = 100667392ull;   // 1048576*96 + 4096 slack
    const size_t WGTB  = 4194304ull;

    unsigned short* pw0 = (unsigned short*)d_ws;
    unsigned short* pw1 = pw0 + 16*64*8;
    unsigned short* pw2 = pw1 + 32*64*8;

    prepack<<<4, 256, 0, stream>>>((const float*)d_in[5], pw0,  39, 128, 128, 8, 2);
    prepack<<<8, 256, 0, stream>>>((const float*)d_in[7], pw1, 128, 128, 128, 8, 4);
    prepack<<<1, 256, 0, stream>>>((const float*)d_in[9], pw2, 128,   3,   3, 1, 4);

    if (ws_size >= PWB + PACKB + FEATB + WGTB) {
        unsigned short* pk0  = (unsigned short*)((char*)d_ws + PWB);
        unsigned short* feat = (unsigned short*)((char*)d_ws + PWB + PACKB);
        float*          wgt  = (float*)((char*)d_ws + PWB + PACKB + FEATB);

        pack_k0<<<(GR3 + 255)/256, 256, 0, stream>>>((const float*)d_in[4], pk0);

        voxgo_gather<<<NRAYS, 256, 0, stream>>>(
            (const float*)d_in[0], (const float*)d_in[1], (const float*)d_in[2],
            (const float*)d_in[3], pk0, feat, wgt, (float*)d_out);

        voxgo_mlp<<<NRAYS*4, 64, 0, stream>>>(
            feat, wgt,
            (const float*)d_in[6], (const float*)d_in[8], (const float*)d_in[10],
            pw0, pw1, pw2, (float*)d_out);
    } else {
        voxgo_mfma<<<NRAYS, 256, 0, stream>>>(
            (const float*)d_in[0], (const float*)d_in[1], (const float*)d_in[2],
            (const float*)d_in[3], (const float*)d_in[4],
            (const float*)d_in[6], (const float*)d_in[8], (const float*)d_in[10],
            pw0, pw1, pw2, (float*)d_out);
    }
}